// Round 2
// baseline (938.809 us; speedup 1.0000x reference)
//
#include <hip/hip_runtime.h>
#include <hip/hip_bf16.h>

// ---------- types ----------
typedef __attribute__((ext_vector_type(8))) short short8;
typedef __attribute__((ext_vector_type(4))) float f32x4;

#define EMB 128
#define OUT 256
#define NRAD 6
#define NDENSE 3

static __device__ __forceinline__ unsigned short f32_to_bf16(float f) {
    union { float f; unsigned u; } v; v.f = f;
    unsigned r = v.u + 0x7fffu + ((v.u >> 16) & 1u);   // round-nearest-even
    return (unsigned short)(r >> 16);
}
static __device__ __forceinline__ float bf16_to_f32(unsigned short h) {
    union { unsigned u; float f; } v; v.u = ((unsigned)h) << 16;
    return v.f;
}

// ---------- zero counts (replaces hipMemsetAsync; keeps graph fill-free) ----------
__global__ void zero_kernel(int* __restrict__ p, int n) {
    int stride = gridDim.x * blockDim.x;
    for (int i = blockIdx.x * blockDim.x + threadIdx.x; i < n; i += stride) p[i] = 0;
}

// ---------- CSR build ----------
__global__ void hist_kernel(const int* __restrict__ src, int* __restrict__ counts, int E) {
    int stride = gridDim.x * blockDim.x;
    for (int e = blockIdx.x * blockDim.x + threadIdx.x; e < E; e += stride)
        atomicAdd(&counts[src[e]], 1);
}

__global__ __launch_bounds__(1024) void scan_kernel(const int* __restrict__ counts,
                                                    int* __restrict__ offsets, int n) {
    __shared__ int sums[1024];
    int t = threadIdx.x;
    int chunk = (n + 1023) >> 10;
    int lo = t * chunk;
    int hi = lo + chunk; if (hi > n) hi = n;
    int s = 0;
    for (int i = lo; i < hi; ++i) s += counts[i];
    sums[t] = s;
    __syncthreads();
    for (int d = 1; d < 1024; d <<= 1) {
        int v = (t >= d) ? sums[t - d] : 0;
        __syncthreads();
        sums[t] += v;
        __syncthreads();
    }
    int base = (t == 0) ? 0 : sums[t - 1];
    for (int i = lo; i < hi; ++i) { offsets[i] = base; base += counts[i]; }
    if (t == 1023) offsets[n] = base;   // total == E
}

__global__ void scatter_kernel(const int* __restrict__ src, const int* __restrict__ offsets,
                               int* __restrict__ counts /*consumed to 0*/,
                               int* __restrict__ perm, int E) {
    int stride = gridDim.x * blockDim.x;
    for (int e = blockIdx.x * blockDim.x + threadIdx.x; e < E; e += stride) {
        int s = src[e];
        int idx = atomicSub(&counts[s], 1) - 1;   // unique slot within node
        perm[offsets[s] + idx] = e;
    }
}

// ---------- weight prep (f32 -> bf16) ----------
__global__ void prep_w_kernel(const float* __restrict__ Wup, const float* __restrict__ Wd,
                              unsigned short* __restrict__ out) {
    const int n1 = OUT * EMB;
    const int n2 = NDENSE * OUT * OUT;
    int stride = gridDim.x * blockDim.x;
    for (int i = blockIdx.x * blockDim.x + threadIdx.x; i < n1 + n2; i += stride)
        out[i] = f32_to_bf16(i < n1 ? Wup[i] : Wd[i - n1]);
}

// ---------- fused edge transform + per-node gather-sum ----------
// persistent wave-per-node: lane l owns columns 2l, 2l+1.
// Chunked: each lane register-stages perm + 6 rbf floats of ONE edge, then
// per-edge __shfl broadcast (no LDS, no sync). float2 m-loads, deep pipelining.
__global__ __launch_bounds__(256) void edge_accum_kernel(
        const float* __restrict__ m, const float* __restrict__ rbf,
        const int* __restrict__ perm, const int* __restrict__ offsets,
        const float* __restrict__ W_rbf, unsigned* __restrict__ t_pack, int N) {
    const int lane = threadIdx.x & 63;
    const int gw = blockIdx.x * (blockDim.x >> 6) + (threadIdx.x >> 6);
    const int nwaves = gridDim.x * (blockDim.x >> 6);

    // per-lane W_rbf rows for cols 2*lane, 2*lane+1 (12 floats, loaded once)
    const float* wr = W_rbf + lane * 2 * NRAD;
    const float wa0 = wr[0], wa1 = wr[1], wa2 = wr[2], wa3 = wr[3], wa4 = wr[4], wa5 = wr[5];
    const float wb0 = wr[6], wb1 = wr[7], wb2 = wr[8], wb3 = wr[9], wb4 = wr[10], wb5 = wr[11];

    for (int node = gw; node < N; node += nwaves) {
        int beg = offsets[node], end = offsets[node + 1];
        float ax = 0.f, ay = 0.f;
        for (int cb = beg; cb < end; cb += 64) {
            int nn = end - cb; if (nn > 64) nn = 64;
            int pe = 0;
            if (lane < nn) pe = perm[cb + lane];
            const float* rp = rbf + (size_t)pe * NRAD;
            float r0 = rp[0], r1 = rp[1], r2 = rp[2], r3 = rp[3], r4 = rp[4], r5 = rp[5];
#pragma unroll 4
            for (int j = 0; j < nn; ++j) {
                int e = __shfl(pe, j);
                float s0 = __shfl(r0, j), s1 = __shfl(r1, j), s2 = __shfl(r2, j);
                float s3 = __shfl(r3, j), s4 = __shfl(r4, j), s5 = __shfl(r5, j);
                float pa = wa0*s0 + wa1*s1 + wa2*s2 + wa3*s3 + wa4*s4 + wa5*s5;
                float pb = wb0*s0 + wb1*s1 + wb2*s2 + wb3*s3 + wb4*s4 + wb5*s5;
                const float2 mv = *(const float2*)(m + (size_t)e * EMB + 2 * lane);
                ax = fmaf(mv.x, pa, ax);
                ay = fmaf(mv.y, pb, ay);
            }
        }
        unsigned short hx = f32_to_bf16(ax), hy = f32_to_bf16(ay);
        t_pack[(size_t)node * 64 + lane] = (unsigned)hx | ((unsigned)hy << 16);
    }
}

// ---------- bf16 MFMA GEMM: C[M,256] = act(A[M,K] @ Bw^T + bias) ----------
template<int K, int ACT>
__global__ __launch_bounds__(256) void gemm_kernel(
        const unsigned short* __restrict__ A, const unsigned short* __restrict__ Bw,
        const float* __restrict__ bias, unsigned short* __restrict__ C, int M) {
    const int w    = threadIdx.x >> 6;
    const int lane = threadIdx.x & 63;
    const int r     = lane & 15;
    const int khalf = lane >> 4;          // 0..3
    const int row0  = blockIdx.x * 64 + w * 16;

    f32x4 acc[16];
#pragma unroll
    for (int i = 0; i < 16; ++i) acc[i] = (f32x4){0.f, 0.f, 0.f, 0.f};

    const int arow = row0 + r;
    const bool rowok = (arow < M);
    const unsigned short* Arow = A + (size_t)arow * K;

    for (int ks = 0; ks < K; ks += 32) {
        int ka = ks + khalf * 8;
        short8 afrag;
        if (rowok) afrag = *(const short8*)(Arow + ka);
        else       afrag = (short8){0,0,0,0,0,0,0,0};
#pragma unroll
        for (int ct = 0; ct < 16; ++ct) {
            int col = ct * 16 + r;
            short8 bfrag = *(const short8*)(Bw + (size_t)col * K + ka);
            acc[ct] = __builtin_amdgcn_mfma_f32_16x16x32_bf16(afrag, bfrag, acc[ct], 0, 0, 0);
        }
    }

    // epilogue: D layout col=lane&15, row=(lane>>4)*4+reg  [verified m89]
    const int orow_base = row0 + khalf * 4;
#pragma unroll
    for (int ct = 0; ct < 16; ++ct) {
        int col = ct * 16 + r;
        float b = bias ? bias[col] : 0.f;
#pragma unroll
        for (int reg = 0; reg < 4; ++reg) {
            int orow = orow_base + reg;
            if (orow < M) {
                float x = acc[ct][reg] + b;
                if (ACT) x = x / (1.f + __expf(-x));   // silu
                C[(size_t)orow * OUT + col] = f32_to_bf16(x);
            }
        }
    }
}

// ---------- per-graph sum: block per graph, binary search, no atomics ----------
__global__ __launch_bounds__(256) void graph_reduce_kernel(
        const unsigned short* __restrict__ h, const int* __restrict__ gids,
        float* __restrict__ out, int M, int G) {
    int g = blockIdx.x;
    int c = threadIdx.x;
    // lower_bound for g and g+1 over sorted gids[0..M)
    int lo = 0, hi = M;
    while (lo < hi) { int mid = (lo + hi) >> 1; if (gids[mid] < g) lo = mid + 1; else hi = mid; }
    int lo2 = lo, hi2 = M;
    while (lo2 < hi2) { int mid = (lo2 + hi2) >> 1; if (gids[mid] < g + 1) lo2 = mid + 1; else hi2 = mid; }
    float acc = 0.f;
    for (int n = lo; n < lo2; ++n)
        acc += bf16_to_f32(h[(size_t)n * OUT + c]);
    out[(size_t)g * OUT + c] = acc;
}

// ---------- host ----------
extern "C" void kernel_launch(void* const* d_in, const int* in_sizes, int n_in,
                              void* d_out, int out_size, void* d_ws, size_t ws_size,
                              hipStream_t stream) {
    const float* m         = (const float*)d_in[0];
    const float* rbf       = (const float*)d_in[1];
    const int*   src       = (const int*)d_in[2];
    const int*   gids      = (const int*)d_in[3];
    const float* W_rbf     = (const float*)d_in[4];
    const float* W_up      = (const float*)d_in[5];
    const float* W_dense   = (const float*)d_in[6];
    const float* b_dense   = (const float*)d_in[7];
    float* out = (float*)d_out;

    const int E = in_sizes[2];
    const int N = in_sizes[3];
    const int G = out_size / OUT;

    // workspace layout
    size_t off = 0;
    auto alloc = [&](size_t bytes) -> void* {
        void* p = (char*)d_ws + off;
        off += (bytes + 255) & ~(size_t)255;
        return p;
    };
    int* counts  = (int*)alloc((size_t)N * 4);
    int* offsets = (int*)alloc(((size_t)N + 1) * 4);
    int* perm    = (int*)alloc((size_t)E * 4);
    unsigned short* t_bf = (unsigned short*)alloc((size_t)N * EMB * 2);
    unsigned short* h0   = (unsigned short*)alloc((size_t)N * OUT * 2);
    unsigned short* h1   = (unsigned short*)alloc((size_t)N * OUT * 2);
    unsigned short* Wbf  = (unsigned short*)alloc((size_t)(OUT * EMB + NDENSE * OUT * OUT) * 2);
    unsigned short* Wup_bf = Wbf;
    unsigned short* Wd_bf  = Wbf + OUT * EMB;

    // CSR build (counts zeroed by our own kernel; no rocclr fills in graph)
    zero_kernel<<<256, 256, 0, stream>>>(counts, N);
    hist_kernel<<<1024, 256, 0, stream>>>(src, counts, E);
    scan_kernel<<<1, 1024, 0, stream>>>(counts, offsets, N);
    scatter_kernel<<<1024, 256, 0, stream>>>(src, offsets, counts, perm, E);

    // weights -> bf16
    prep_w_kernel<<<256, 256, 0, stream>>>(W_up, W_dense, Wbf);

    // edge transform + node gather (persistent, 8192 waves = 32/CU)
    edge_accum_kernel<<<2048, 256, 0, stream>>>(m, rbf, perm, offsets, W_rbf,
                                                (unsigned*)t_bf, N);

    // up-projection (no bias, no act), then 3 dense+silu layers
    int gblocks = (N + 63) / 64;
    gemm_kernel<EMB, 0><<<gblocks, 256, 0, stream>>>(t_bf, Wup_bf, nullptr, h0, N);
    gemm_kernel<OUT, 1><<<gblocks, 256, 0, stream>>>(h0, Wd_bf + 0 * OUT * OUT, b_dense + 0 * OUT, h1, N);
    gemm_kernel<OUT, 1><<<gblocks, 256, 0, stream>>>(h1, Wd_bf + 1 * OUT * OUT, b_dense + 1 * OUT, h0, N);
    gemm_kernel<OUT, 1><<<gblocks, 256, 0, stream>>>(h0, Wd_bf + 2 * OUT * OUT, b_dense + 2 * OUT, h1, N);

    // per-graph readout (deterministic, atomic-free)
    graph_reduce_kernel<<<G, 256, 0, stream>>>(h1, gids, out, N, G);
}